// Round 7
// baseline (585.577 us; speedup 1.0000x reference)
//
#include <hip/hip_runtime.h>
#include <hip/hip_bf16.h>
#include <cmath>

#define C_DIM 96
#define RES_D 16
#define RES_H 56
#define RES_W 56
#define BATCH 4
#define SPATIAL (RES_D*RES_H*RES_W)      // 50176
#define NTOK (BATCH*SPATIAL)             // 200704
#define NWIN_TOT 2048
#define EPS_LN 1e-5f
#define QSCALE 0.2041241452319315f       // 1/sqrt(24)

#define MPAD 112        // window tokens padded 98 -> 112 (7 M-tiles, 7 waves)

// LDS layout (u16 element offsets)
#define OFF_P   0              // [112][128]  P only (x-hat lives in registers)
#define OFF_Q   14336          // [2][112][32] q pair-slots; later O [112][128] overlay
#define OFF_K   21504          // [2][112][32] k pair-slots
#define OFF_VT  28672          // [64][128]   v^T pair (2 heads x 32 d-rows)
#define SM_TOT  36864

typedef float f32x4 __attribute__((ext_vector_type(4)));
typedef short s16x8 __attribute__((ext_vector_type(8)));
typedef unsigned u32x4 __attribute__((ext_vector_type(4)));
typedef unsigned short u16;

__device__ __forceinline__ u16 f2bf(float f) {
    unsigned u = __float_as_uint(f);
    u = (u + 0x7FFF + ((u >> 16) & 1)) >> 16;
    return (u16)u;
}
// chunk-swizzled addressing: [r][128] bf16, 16B chunks XOR'd by row
__device__ __forceinline__ int swzP(int r, int c) {
    return r * 128 + ((((c >> 3) ^ (r & 15)) << 3) | (c & 7));
}
// [r][32] bf16 buffers (q/k)
__device__ __forceinline__ int swzQ(int r, int c) {
    return r * 32 + ((((c >> 3) ^ ((r >> 1) & 3)) << 3) | (c & 7));
}

__device__ __forceinline__ float wave_reduce_sum(float v) {
#pragma unroll
    for (int off = 32; off > 0; off >>= 1) v += __shfl_xor(v, off, 64);
    return v;
}

// ---------------- prep: bf16-transpose weights + dense rpb matrix ----------------
// rpbm[h][128][128]: col-pad (m>=98) = -30000 (exp->0); row-pad (n>=98) = 0.
__global__ __launch_bounds__(256) void k_prep(
    const float* __restrict__ qkv_w, const float* __restrict__ proj_w,
    const float* __restrict__ fc1_w, const float* __restrict__ fc2_w,
    const float* __restrict__ rpb_table,
    u16* __restrict__ wq, u16* __restrict__ wp, u16* __restrict__ w1,
    u16* __restrict__ w2, float* __restrict__ rpbm) {
    int i = blockIdx.x * 256 + threadIdx.x;
    if (i < 27648) {
        int j = i / 96, c = i % 96;
        wq[i] = f2bf(qkv_w[c * 288 + j]);
    } else if (i < 36864) {
        int t = i - 27648; int j = t / 96, c = t % 96;
        wp[t] = f2bf(proj_w[c * 96 + j]);
    } else if (i < 73728) {
        int t = i - 36864; int j = t / 96, c = t % 96;
        w1[t] = f2bf(fc1_w[c * 384 + j]);
    } else if (i < 110592) {
        int t = i - 73728; int c = t / 384, j = t % 384;
        w2[t] = f2bf(fc2_w[j * 96 + c]);
    } else if (i < 176128) {
        int t = i - 110592;
        int h = t / 16384, r = t % 16384, n = r / 128, m = r % 128;
        float v;
        if (m >= 98) {
            v = -30000.0f;                 // col pad: exp -> 0
        } else if (n >= 98) {
            v = 0.0f;                      // row pad: harmless finite scores
        } else {
            int dzn = n / 49, rn = n % 49, hyn = rn / 7, wxn = rn % 7;
            int dzm = m / 49, rm = m % 49, hym = rm / 7, wxm = rm % 7;
            int ridx = (dzn - dzm + 1) * 169 + (hyn - hym + 6) * 13 + (wxn - wxm + 6);
            v = rpb_table[ridx * 4 + h];
        }
        rpbm[t] = v;
    }
}

// ---------------- (B,C,S) -> (B,S,C) transpose ----------------
__global__ __launch_bounds__(256) void k_transpose_in(const float* __restrict__ x,
                                                      float* __restrict__ xl) {
    __shared__ float tile[32][33];
    const int b = blockIdx.z;
    const int s0 = blockIdx.x * 32;
    const int c0 = blockIdx.y * 32;
    const float* xb = x + (size_t)b * C_DIM * SPATIAL;
    float* xlb = xl + (size_t)b * SPATIAL * C_DIM;
    const int ts = threadIdx.x, tc = threadIdx.y;
#pragma unroll
    for (int i = 0; i < 32; i += 8)
        tile[tc + i][ts] = xb[(size_t)(c0 + tc + i) * SPATIAL + s0 + ts];
    __syncthreads();
#pragma unroll
    for (int i = 0; i < 32; i += 8)
        xlb[(size_t)(s0 + tc + i) * C_DIM + c0 + ts] = tile[ts][tc + i];
}

// ---------------- per-window attention ----------------
// Streaming no-max softmax (bounded scores), unnormalized P, 1/sum folded into PV.
// __launch_bounds__(448, 4): total reg budget 128/wave -> 4 waves/SIMD -> 2 blocks/CU.
__global__ __launch_bounds__(448, 4) void k_win_attn(
    const float* __restrict__ xl, float* __restrict__ xl2,
    const float* __restrict__ g1, const float* __restrict__ b1,
    const u16* __restrict__ wqkv, const float* __restrict__ qkv_b,
    const u16* __restrict__ wproj, const float* __restrict__ proj_b,
    const float* __restrict__ rpbm) {
    __shared__ __align__(16) u16 sm[SM_TOT];
    __shared__ int s_gtok[MPAD];
    __shared__ int s_reg[MPAD];

    const int tid = threadIdx.x;
    const int lane = tid & 63;
    const int wv = tid >> 6;            // 0..6, owns M-tile wv
    const int g4 = lane >> 4;
    const int c16 = lane & 15;
    const int mt = wv;

    const int wid = blockIdx.x;
    const int b = wid >> 9;
    const int rem = wid & 511;
    const int wdi = rem >> 6, whi = (rem >> 3) & 7, wwi = rem & 7;

    // ---- targeted zeroing (pads only) ----
    for (int i = tid; i < 1792; i += 448) {            // P cols 112..127 (never written later)
        int r = i >> 4, c = 112 + (i & 15);
        sm[OFF_P + swzP(r, c)] = 0;
    }
    for (int i = tid; i < 3584; i += 448) {            // q/k pad cols 24..31 (both slots)
        int c = 24 + (i & 7);
        int r = (i >> 3) % 112;
        int slot = (i >> 3) / 112;
        int base = (slot < 2) ? (OFF_Q + slot * 3584) : (OFF_K + (slot - 2) * 3584);
        sm[base + swzQ(r, c)] = 0;
    }
    for (int i = tid; i < 2048; i += 448) {            // vt pad d-rows 24..31 / 56..63
        int rr = i >> 7, c = i & 127;
        int r = (rr < 8) ? (24 + rr) : (48 + rr);
        sm[OFF_VT + swzP(r, c)] = 0;
    }
    for (int i = tid; i < 1024; i += 448) {            // vt token-cols 112..127
        int r = i >> 4, c = 112 + (i & 15);
        sm[OFF_VT + swzP(r, c)] = 0;
    }
    if (tid < MPAD) {
        if (tid < 98) {
            const int n = tid;
            const int dz = n / 49, r = n % 49, hy = r / 7, wx = r % 7;
            const int rd = wdi * 2 + dz, rh = whi * 7 + hy, rw = wwi * 7 + wx;
            int od = rd + 1; if (od >= RES_D) od -= RES_D;
            int oh = rh + 3; if (oh >= RES_H) oh -= RES_H;
            int ow = rw + 3; if (ow >= RES_W) ow -= RES_W;
            s_gtok[n] = ((b * RES_D + od) * RES_H + oh) * RES_W + ow;
            const int gd = (rd < 14) ? 0 : (rd < 15 ? 1 : 2);
            const int gh = (rh < 49) ? 0 : (rh < 53 ? 1 : 2);
            const int gw = (rw < 49) ? 0 : (rw < 53 ? 1 : 2);
            s_reg[n] = gd * 9 + gh * 3 + gw;
        } else { s_gtok[tid] = 0; s_reg[tid] = -1; }
    }
    __syncthreads();

    // ---- LN1 -> registers, A-fragment layout (row = mt*16+c16, cols ks*32+g4*8) ----
    const int myrow = mt * 16 + c16;
    const float live = (myrow < 98) ? 1.0f : 0.0f;
    u32x4 xa[3];
    {
        const float* src = xl + (size_t)s_gtok[myrow] * C_DIM;
        f32x4 xv0 = *(const f32x4*)(src + 0 * 32 + g4 * 8);
        f32x4 xv1 = *(const f32x4*)(src + 0 * 32 + g4 * 8 + 4);
        f32x4 xv2 = *(const f32x4*)(src + 1 * 32 + g4 * 8);
        f32x4 xv3 = *(const f32x4*)(src + 1 * 32 + g4 * 8 + 4);
        f32x4 xv4 = *(const f32x4*)(src + 2 * 32 + g4 * 8);
        f32x4 xv5 = *(const f32x4*)(src + 2 * 32 + g4 * 8 + 4);
        float lsum = (xv0[0]+xv0[1]+xv0[2]+xv0[3]) + (xv1[0]+xv1[1]+xv1[2]+xv1[3])
                   + (xv2[0]+xv2[1]+xv2[2]+xv2[3]) + (xv3[0]+xv3[1]+xv3[2]+xv3[3])
                   + (xv4[0]+xv4[1]+xv4[2]+xv4[3]) + (xv5[0]+xv5[1]+xv5[2]+xv5[3]);
        lsum += __shfl_xor(lsum, 16, 64);
        lsum += __shfl_xor(lsum, 32, 64);
        const float mu = lsum * (1.0f / 96.0f);
        f32x4 d0 = xv0 - mu, d1 = xv1 - mu, d2 = xv2 - mu,
              d3 = xv3 - mu, d4 = xv4 - mu, d5 = xv5 - mu;
        float lvv = (d0[0]*d0[0]+d0[1]*d0[1]+d0[2]*d0[2]+d0[3]*d0[3])
                  + (d1[0]*d1[0]+d1[1]*d1[1]+d1[2]*d1[2]+d1[3]*d1[3])
                  + (d2[0]*d2[0]+d2[1]*d2[1]+d2[2]*d2[2]+d2[3]*d2[3])
                  + (d3[0]*d3[0]+d3[1]*d3[1]+d3[2]*d3[2]+d3[3]*d3[3])
                  + (d4[0]*d4[0]+d4[1]*d4[1]+d4[2]*d4[2]+d4[3]*d4[3])
                  + (d5[0]*d5[0]+d5[1]*d5[1]+d5[2]*d5[2]+d5[3]*d5[3]);
        lvv += __shfl_xor(lvv, 16, 64);
        lvv += __shfl_xor(lvv, 32, 64);
        const float rstd = rsqrtf(lvv * (1.0f / 96.0f) + EPS_LN) * live;
#pragma unroll
        for (int ks = 0; ks < 3; ++ks) {
            const f32x4 ea = (ks == 0) ? d0 : (ks == 1) ? d2 : d4;
            const f32x4 eb = (ks == 0) ? d1 : (ks == 1) ? d3 : d5;
            f32x4 ga = *(const f32x4*)(g1 + ks * 32 + g4 * 8);
            f32x4 gb = *(const f32x4*)(g1 + ks * 32 + g4 * 8 + 4);
            f32x4 ba = *(const f32x4*)(b1 + ks * 32 + g4 * 8);
            f32x4 bb = *(const f32x4*)(b1 + ks * 32 + g4 * 8 + 4);
            f32x4 y0 = ea * rstd * ga + ba * live;
            f32x4 y1 = eb * rstd * gb + bb * live;
            xa[ks][0] = (unsigned)f2bf(y0[0]) | ((unsigned)f2bf(y0[1]) << 16);
            xa[ks][1] = (unsigned)f2bf(y0[2]) | ((unsigned)f2bf(y0[3]) << 16);
            xa[ks][2] = (unsigned)f2bf(y1[0]) | ((unsigned)f2bf(y1[1]) << 16);
            xa[ks][3] = (unsigned)f2bf(y1[2]) | ((unsigned)f2bf(y1[3]) << 16);
        }
    }

    // ---- head pairs: QKV(pair) from registers -> attention(pair) ----
    unsigned ogp[4][2][2];
#pragma unroll
    for (int p = 0; p < 2; ++p) {
#pragma unroll
        for (int sel = 0; sel < 3; ++sel) {
#pragma unroll
            for (int t = 0; t < 3; ++t) {
                const int nt = sel * 6 + p * 3 + t;
                f32x4 acc = {0.f, 0.f, 0.f, 0.f};
#pragma unroll
                for (int ks = 0; ks < 3; ++ks) {
                    s16x8 a = __builtin_bit_cast(s16x8, xa[ks]);
                    s16x8 bw = *(const s16x8*)(wqkv + (size_t)(nt * 16 + c16) * 96 + ks * 32 + g4 * 8);
                    acc = __builtin_amdgcn_mfma_f32_16x16x32_bf16(a, bw, acc, 0, 0, 0);
                }
                const float bias = qkv_b[nt * 16 + c16];
                float v0 = acc[0] + bias, v1 = acc[1] + bias, v2 = acc[2] + bias, v3 = acc[3] + bias;
                if (sel == 0) { v0 *= QSCALE; v1 *= QSCALE; v2 *= QSCALE; v3 *= QSCALE; }
                const int l48 = t * 16 + c16;
                const int hp = l48 / 24, d = l48 - hp * 24;
                const int row0 = mt * 16 + g4 * 4;
                if (sel == 0) {
                    sm[OFF_Q + hp * 3584 + swzQ(row0 + 0, d)] = f2bf(v0);
                    sm[OFF_Q + hp * 3584 + swzQ(row0 + 1, d)] = f2bf(v1);
                    sm[OFF_Q + hp * 3584 + swzQ(row0 + 2, d)] = f2bf(v2);
                    sm[OFF_Q + hp * 3584 + swzQ(row0 + 3, d)] = f2bf(v3);
                } else if (sel == 1) {
                    sm[OFF_K + hp * 3584 + swzQ(row0 + 0, d)] = f2bf(v0);
                    sm[OFF_K + hp * 3584 + swzQ(row0 + 1, d)] = f2bf(v1);
                    sm[OFF_K + hp * 3584 + swzQ(row0 + 2, d)] = f2bf(v2);
                    sm[OFF_K + hp * 3584 + swzQ(row0 + 3, d)] = f2bf(v3);
                } else {
                    sm[OFF_VT + swzP(hp * 32 + d, row0 + 0)] = f2bf(v0);
                    sm[OFF_VT + swzP(hp * 32 + d, row0 + 1)] = f2bf(v1);
                    sm[OFF_VT + swzP(hp * 32 + d, row0 + 2)] = f2bf(v2);
                    sm[OFF_VT + swzP(hp * 32 + d, row0 + 3)] = f2bf(v3);
                }
            }
        }
        __syncthreads();

#pragma unroll
        for (int hp = 0; hp < 2; ++hp) {
            const int h = p * 2 + hp;
            const s16x8 aq = *(const s16x8*)&sm[OFF_Q + hp * 3584 + swzQ(mt * 16 + c16, g4 * 8)];
            const float* rh = rpbm + h * 16384;
            const int rbase = mt * 16 + g4 * 4;
            int rgs[4];
#pragma unroll
            for (int r = 0; r < 4; ++r) rgs[r] = s_reg[rbase + r];
            float smr[4] = {0.f, 0.f, 0.f, 0.f};
            // streaming no-max softmax: e = exp(s), write unnormalized P, track sum
#pragma unroll
            for (int nt = 0; nt < 7; ++nt) {
                s16x8 bk = *(const s16x8*)&sm[OFF_K + hp * 3584 + swzQ(nt * 16 + c16, g4 * 8)];
                f32x4 z = {0.f, 0.f, 0.f, 0.f};
                f32x4 sc = __builtin_amdgcn_mfma_f32_16x16x32_bf16(aq, bk, z, 0, 0, 0);
                const int col = nt * 16 + c16;
                const int creg = s_reg[col];
#pragma unroll
                for (int r = 0; r < 4; ++r) {
                    float s = sc[r] + rh[(rbase + r) * 128 + col];
                    if (rgs[r] != creg) s -= 100.0f;
                    const float e = __expf(s);
                    sc[r] = e;
                    smr[r] += e;
                }
                sm[OFF_P + swzP(rbase + 0, col)] = f2bf(sc[0]);
                sm[OFF_P + swzP(rbase + 1, col)] = f2bf(sc[1]);
                sm[OFF_P + swzP(rbase + 2, col)] = f2bf(sc[2]);
                sm[OFF_P + swzP(rbase + 3, col)] = f2bf(sc[3]);
            }
#pragma unroll
            for (int r = 0; r < 4; ++r) {
#pragma unroll
                for (int m = 1; m <= 8; m <<= 1) smr[r] += __shfl_xor(smr[r], m, 64);
                smr[r] = 1.0f / fmaxf(smr[r], 1e-30f);   // guard dead pad rows
            }
#pragma unroll
            for (int dt = 0; dt < 2; ++dt) {
                f32x4 acc = {0.f, 0.f, 0.f, 0.f};
#pragma unroll
                for (int ks = 0; ks < 4; ++ks) {
                    s16x8 ap = *(const s16x8*)&sm[OFF_P + swzP(mt * 16 + c16, ks * 32 + g4 * 8)];
                    s16x8 bv = *(const s16x8*)&sm[OFF_VT + swzP(hp * 32 + dt * 16 + c16, ks * 32 + g4 * 8)];
                    acc = __builtin_amdgcn_mfma_f32_16x16x32_bf16(ap, bv, acc, 0, 0, 0);
                }
                ogp[h][dt][0] = (unsigned)f2bf(acc[0] * smr[0]) | ((unsigned)f2bf(acc[1] * smr[1]) << 16);
                ogp[h][dt][1] = (unsigned)f2bf(acc[2] * smr[2]) | ((unsigned)f2bf(acc[3] * smr[3]) << 16);
            }
        }
        __syncthreads();        // p=0: before pair-1 QKV overwrite; p=1: before O overlay
    }

    // ---- O -> q+k region as [112][128] ----
#pragma unroll
    for (int h = 0; h < 4; ++h) {
#pragma unroll
        for (int dt = 0; dt < 2; ++dt) {
            const int d = dt * 16 + c16;
            if (d < 24) {
                const int col = h * 24 + d;
#pragma unroll
                for (int rp = 0; rp < 2; ++rp) {
                    const unsigned u = ogp[h][dt][rp];
                    const int row0 = mt * 16 + g4 * 4 + rp * 2;
                    sm[OFF_Q + swzP(row0, col)] = (u16)u;
                    sm[OFF_Q + swzP(row0 + 1, col)] = (u16)(u >> 16);
                }
            }
        }
    }
    // own-tile rows only -> no barrier needed before proj

    // ---- proj + residual -> xl2 ----
#pragma unroll
    for (int nt = 0; nt < 6; ++nt) {
        f32x4 acc = {0.f, 0.f, 0.f, 0.f};
#pragma unroll
        for (int ks = 0; ks < 3; ++ks) {
            s16x8 a = *(const s16x8*)&sm[OFF_Q + swzP(mt * 16 + c16, ks * 32 + g4 * 8)];
            s16x8 bw = *(const s16x8*)(wproj + (size_t)(nt * 16 + c16) * 96 + ks * 32 + g4 * 8);
            acc = __builtin_amdgcn_mfma_f32_16x16x32_bf16(a, bw, acc, 0, 0, 0);
        }
        const int col = nt * 16 + c16;
        const float pb = proj_b[col];
#pragma unroll
        for (int r = 0; r < 4; ++r) {
            const int row = mt * 16 + g4 * 4 + r;
            if (row < 98) {
                const size_t base = (size_t)s_gtok[row] * C_DIM + col;
                xl2[base] = xl[base] + acc[r] + pb;
            }
        }
    }
}

// ---------------- FFN: LN2 + FC1 + GELU + FC2 + residual + transposed out ----------------
__global__ __launch_bounds__(256) void k_ffn(
    const float* __restrict__ xl2, float* __restrict__ out,
    const float* __restrict__ g2, const float* __restrict__ b2,
    const u16* __restrict__ w1, const float* __restrict__ fc1_b,
    const u16* __restrict__ w2, const float* __restrict__ fc2_b) {
    __shared__ char smem[25088 + 12800];
    u16* s_g = (u16*)smem;                    // [32][392] bf16
    u16* s_h = (u16*)(smem + 25088);          // [32][104] bf16, dead after FC1
    float* s_res = (float*)(smem + 25088);    // [32][100] f32, aliases s_h

    const int tid = threadIdx.x;
    const int lane = tid & 63;
    const int wave = tid >> 6;
    const int g4 = lane >> 4, c16 = lane & 15;
    const int mt = wave & 1;
    const int nh = wave >> 1;
    const int t0 = blockIdx.x * 32;

    for (int n = wave; n < 32; n += 4) {
        const size_t base = (size_t)(t0 + n) * C_DIM;
        const float v0 = xl2[base + lane];
        const float v1 = (lane < 32) ? xl2[base + 64 + lane] : 0.0f;
        const float mu = wave_reduce_sum(v0 + v1) * (1.0f / 96.0f);
        const float d0 = v0 - mu;
        const float d1 = (lane < 32) ? (v1 - mu) : 0.0f;
        const float var = wave_reduce_sum(d0 * d0 + d1 * d1) * (1.0f / 96.0f);
        const float rstd = rsqrtf(var + EPS_LN);
        s_h[n * 104 + lane] = f2bf(d0 * rstd * g2[lane] + b2[lane]);
        if (lane < 32) s_h[n * 104 + 64 + lane] = f2bf(d1 * rstd * g2[64 + lane] + b2[64 + lane]);
    }
    __syncthreads();

#pragma unroll 1
    for (int i = 0; i < 12; ++i) {
        const int nt = nh * 12 + i;
        f32x4 acc = {0.f, 0.f, 0.f, 0.f};
#pragma unroll
        for (int ks = 0; ks < 3; ++ks) {
            s16x8 a = *(const s16x8*)(&s_h[(mt * 16 + c16) * 104 + ks * 32 + g4 * 8]);
            s16x8 bw = *(const s16x8*)(w1 + (size_t)(nt * 16 + c16) * 96 + ks * 32 + g4 * 8);
            acc = __builtin_amdgcn_mfma_f32_16x16x32_bf16(a, bw, acc, 0, 0, 0);
        }
        const int col = nt * 16 + c16;
        const float bias = fc1_b[col];
#pragma unroll
        for (int r = 0; r < 4; ++r) {
            const float v = acc[r] + bias;
            const float gelu = 0.5f * v * (1.0f + erff(v * 0.70710678118654752f));
            s_g[(mt * 16 + g4 * 4 + r) * 392 + col] = f2bf(gelu);
        }
    }
    __syncthreads();

#pragma unroll 1
    for (int i = 0; i < 3; ++i) {
        const int nt = nh * 3 + i;
        f32x4 acc = {0.f, 0.f, 0.f, 0.f};
#pragma unroll
        for (int ks = 0; ks < 12; ++ks) {
            s16x8 a = *(const s16x8*)(&s_g[(mt * 16 + c16) * 392 + ks * 32 + g4 * 8]);
            s16x8 bw = *(const s16x8*)(w2 + (size_t)(nt * 16 + c16) * 384 + ks * 32 + g4 * 8);
            acc = __builtin_amdgcn_mfma_f32_16x16x32_bf16(a, bw, acc, 0, 0, 0);
        }
        const int col = nt * 16 + c16;
        const float bias = fc2_b[col];
#pragma unroll
        for (int r = 0; r < 4; ++r) {
            const int row = mt * 16 + g4 * 4 + r;
            s_res[row * 100 + col] = acc[r] + bias + xl2[(size_t)(t0 + row) * C_DIM + col];
        }
    }
    __syncthreads();

    const int bb = t0 / SPATIAL;
    const int sbase = t0 % SPATIAL;
    for (int idx = tid; idx < 96 * 32; idx += 256) {
        const int c = idx >> 5, tok = idx & 31;
        out[((size_t)bb * C_DIM + c) * SPATIAL + sbase + tok] = s_res[tok * 100 + c];
    }
}

extern "C" void kernel_launch(void* const* d_in, const int* in_sizes, int n_in,
                              void* d_out, int out_size, void* d_ws, size_t ws_size,
                              hipStream_t stream) {
    const float* x      = (const float*)d_in[0];
    const float* g1     = (const float*)d_in[1];
    const float* be1    = (const float*)d_in[2];
    const float* g2     = (const float*)d_in[3];
    const float* be2    = (const float*)d_in[4];
    const float* qkv_w  = (const float*)d_in[5];
    const float* qkv_b  = (const float*)d_in[6];
    const float* proj_w = (const float*)d_in[7];
    const float* proj_b = (const float*)d_in[8];
    const float* rpb    = (const float*)d_in[9];
    const float* fc1_w  = (const float*)d_in[10];
    const float* fc1_b  = (const float*)d_in[11];
    const float* fc2_w  = (const float*)d_in[12];
    const float* fc2_b  = (const float*)d_in[13];
    float* out = (float*)d_out;

    float* xl  = (float*)d_ws;
    float* xl2 = xl + (size_t)NTOK * C_DIM;
    u16* wq = (u16*)(xl2 + (size_t)NTOK * C_DIM);
    u16* wp = wq + 27648;
    u16* w1 = wp + 9216;
    u16* w2 = w1 + 36864;
    float* rpbm = (float*)(w2 + 36864);

    k_prep<<<688, 256, 0, stream>>>(qkv_w, proj_w, fc1_w, fc2_w, rpb, wq, wp, w1, w2, rpbm);
    k_transpose_in<<<dim3(SPATIAL / 32, C_DIM / 32, BATCH), dim3(32, 8), 0, stream>>>(x, xl);
    k_win_attn<<<NWIN_TOT, 448, 0, stream>>>(xl, xl2, g1, be1, wq, qkv_b, wp, proj_b, rpbm);
    k_ffn<<<NTOK / 32, 256, 0, stream>>>(xl2, out, g2, be2, w1, fc1_b, w2, fc2_b);
}

// Round 9
// 427.465 us; speedup vs baseline: 1.3699x; 1.3699x over previous
//
#include <hip/hip_runtime.h>
#include <hip/hip_bf16.h>
#include <cmath>

#define C_DIM 96
#define RES_D 16
#define RES_H 56
#define RES_W 56
#define BATCH 4
#define SPATIAL (RES_D*RES_H*RES_W)      // 50176
#define NTOK (BATCH*SPATIAL)             // 200704
#define NWIN_TOT 2048
#define EPS_LN 1e-5f
#define QSCALE 0.2041241452319315f       // 1/sqrt(24)

#define MPAD 112        // window tokens padded 98 -> 112 (7 M-tiles, 7 waves)

// LDS layout (u16 element offsets) — full 4-head buffers, 1 block/CU by design
#define OFF_P   0              // [112][128]  P; later O overlay (own rows)
#define OFF_Q   14336          // [4][112][32] q head-slabs
#define OFF_K   28672          // [4][112][32] k head-slabs
#define OFF_VT  43008          // [4][32][128] v^T head-slabs
#define SM_TOT  59392          // 118784 B

typedef float f32x4 __attribute__((ext_vector_type(4)));
typedef short s16x8 __attribute__((ext_vector_type(8)));
typedef unsigned u32x4 __attribute__((ext_vector_type(4)));
typedef unsigned short u16;

__device__ __forceinline__ u16 f2bf(float f) {
    unsigned u = __float_as_uint(f);
    u = (u + 0x7FFF + ((u >> 16) & 1)) >> 16;
    return (u16)u;
}
// chunk-swizzled addressing: [r][128] bf16, 16B chunks XOR'd by row
__device__ __forceinline__ int swzP(int r, int c) {
    return r * 128 + ((((c >> 3) ^ (r & 15)) << 3) | (c & 7));
}
// [r][32] bf16 buffers (q/k)
__device__ __forceinline__ int swzQ(int r, int c) {
    return r * 32 + ((((c >> 3) ^ ((r >> 1) & 3)) << 3) | (c & 7));
}

__device__ __forceinline__ float wave_reduce_sum(float v) {
#pragma unroll
    for (int off = 32; off > 0; off >>= 1) v += __shfl_xor(v, off, 64);
    return v;
}

// ---------------- prep: bf16-transpose weights + dense rpb matrix ----------------
// rpbm[h][128][128]: col-pad (m>=98) = -30000 (exp->0); row-pad (n>=98) = 0.
__global__ __launch_bounds__(256) void k_prep(
    const float* __restrict__ qkv_w, const float* __restrict__ proj_w,
    const float* __restrict__ fc1_w, const float* __restrict__ fc2_w,
    const float* __restrict__ rpb_table,
    u16* __restrict__ wq, u16* __restrict__ wp, u16* __restrict__ w1,
    u16* __restrict__ w2, float* __restrict__ rpbm) {
    int i = blockIdx.x * 256 + threadIdx.x;
    if (i < 27648) {
        int j = i / 96, c = i % 96;
        wq[i] = f2bf(qkv_w[c * 288 + j]);
    } else if (i < 36864) {
        int t = i - 27648; int j = t / 96, c = t % 96;
        wp[t] = f2bf(proj_w[c * 96 + j]);
    } else if (i < 73728) {
        int t = i - 36864; int j = t / 96, c = t % 96;
        w1[t] = f2bf(fc1_w[c * 384 + j]);
    } else if (i < 110592) {
        int t = i - 73728; int c = t / 384, j = t % 384;
        w2[t] = f2bf(fc2_w[j * 96 + c]);
    } else if (i < 176128) {
        int t = i - 110592;
        int h = t / 16384, r = t % 16384, n = r / 128, m = r % 128;
        float v;
        if (m >= 98) {
            v = -30000.0f;                 // col pad: exp -> 0
        } else if (n >= 98) {
            v = 0.0f;                      // row pad: harmless finite scores
        } else {
            int dzn = n / 49, rn = n % 49, hyn = rn / 7, wxn = rn % 7;
            int dzm = m / 49, rm = m % 49, hym = rm / 7, wxm = rm % 7;
            int ridx = (dzn - dzm + 1) * 169 + (hyn - hym + 6) * 13 + (wxn - wxm + 6);
            v = rpb_table[ridx * 4 + h];
        }
        rpbm[t] = v;
    }
}

// ---------------- (B,C,S) -> (B,S,C) transpose ----------------
__global__ __launch_bounds__(256) void k_transpose_in(const float* __restrict__ x,
                                                      float* __restrict__ xl) {
    __shared__ float tile[32][33];
    const int b = blockIdx.z;
    const int s0 = blockIdx.x * 32;
    const int c0 = blockIdx.y * 32;
    const float* xb = x + (size_t)b * C_DIM * SPATIAL;
    float* xlb = xl + (size_t)b * SPATIAL * C_DIM;
    const int ts = threadIdx.x, tc = threadIdx.y;
#pragma unroll
    for (int i = 0; i < 32; i += 8)
        tile[tc + i][ts] = xb[(size_t)(c0 + tc + i) * SPATIAL + s0 + ts];
    __syncthreads();
#pragma unroll
    for (int i = 0; i < 32; i += 8)
        xlb[(size_t)(s0 + tc + i) * C_DIM + c0 + ts] = tile[ts][tc + i];
}

// ---------------- per-window attention ----------------
// Single QKV phase -> 4-head barrier-free attention (own-row P discipline).
// 119KB LDS, 1 block/CU by design; 3 barriers total.
__global__ __launch_bounds__(448, 2) void k_win_attn(
    const float* __restrict__ xl, float* __restrict__ xl2,
    const float* __restrict__ g1, const float* __restrict__ b1,
    const u16* __restrict__ wqkv, const float* __restrict__ qkv_b,
    const u16* __restrict__ wproj, const float* __restrict__ proj_b,
    const float* __restrict__ rpbm) {
    __shared__ __align__(16) u16 sm[SM_TOT];
    __shared__ int s_gtok[MPAD];
    __shared__ int s_reg[MPAD];

    const int tid = threadIdx.x;
    const int lane = tid & 63;
    const int wv = tid >> 6;            // 0..6, owns M-tile wv
    const int g4 = lane >> 4;
    const int c16 = lane & 15;
    const int mt = wv;

    const int wid = blockIdx.x;
    const int b = wid >> 9;
    const int rem = wid & 511;
    const int wdi = rem >> 6, whi = (rem >> 3) & 7, wwi = rem & 7;

    // ---- targeted zeroing (pads only) ----
    for (int i = tid; i < 7168; i += 448) {            // q/k pad cols 24..31, 4 slabs each
        int c = 24 + (i & 7);
        int hb = (i >> 3) / 112;                        // 0..7
        int r = (i >> 3) % 112;
        int base = (hb < 4) ? (OFF_Q + hb * 3584) : (OFF_K + (hb - 4) * 3584);
        sm[base + swzQ(r, c)] = 0;
    }
    for (int i = tid; i < 4096; i += 448) {            // vt pad d-rows 24..31 (all cols)
        int h = i >> 10, rr = 24 + ((i >> 7) & 7), c = i & 127;
        sm[OFF_VT + h * 4096 + swzP(rr, c)] = 0;
    }
    for (int i = tid; i < 1536; i += 448) {            // vt tok-cols 112..127, d-rows 0..23
        int h = i / 384, r = (i % 384) >> 4, c = 112 + (i & 15);
        sm[OFF_VT + h * 4096 + swzP(r, c)] = 0;
    }
    for (int i = tid; i < 1792; i += 448) {            // P cols 112..127
        int r = i >> 4, c = 112 + (i & 15);
        sm[OFF_P + swzP(r, c)] = 0;
    }
    if (tid < MPAD) {
        if (tid < 98) {
            const int n = tid;
            const int dz = n / 49, r = n % 49, hy = r / 7, wx = r % 7;
            const int rd = wdi * 2 + dz, rh = whi * 7 + hy, rw = wwi * 7 + wx;
            int od = rd + 1; if (od >= RES_D) od -= RES_D;
            int oh = rh + 3; if (oh >= RES_H) oh -= RES_H;
            int ow = rw + 3; if (ow >= RES_W) ow -= RES_W;
            s_gtok[n] = ((b * RES_D + od) * RES_H + oh) * RES_W + ow;
            const int gd = (rd < 14) ? 0 : (rd < 15 ? 1 : 2);
            const int gh = (rh < 49) ? 0 : (rh < 53 ? 1 : 2);
            const int gw = (rw < 49) ? 0 : (rw < 53 ? 1 : 2);
            s_reg[n] = gd * 9 + gh * 3 + gw;
        } else { s_gtok[tid] = 0; s_reg[tid] = -1; }
    }
    __syncthreads();                                   // barrier 1 (gtok + pad zeros)

    // ---- LN1 -> registers, A-fragment layout (row = mt*16+c16, cols ks*32+g4*8) ----
    const int myrow = mt * 16 + c16;
    const float live = (myrow < 98) ? 1.0f : 0.0f;
    u32x4 xa[3];
    {
        const float* src = xl + (size_t)s_gtok[myrow] * C_DIM;
        f32x4 xv0 = *(const f32x4*)(src + 0 * 32 + g4 * 8);
        f32x4 xv1 = *(const f32x4*)(src + 0 * 32 + g4 * 8 + 4);
        f32x4 xv2 = *(const f32x4*)(src + 1 * 32 + g4 * 8);
        f32x4 xv3 = *(const f32x4*)(src + 1 * 32 + g4 * 8 + 4);
        f32x4 xv4 = *(const f32x4*)(src + 2 * 32 + g4 * 8);
        f32x4 xv5 = *(const f32x4*)(src + 2 * 32 + g4 * 8 + 4);
        float lsum = (xv0[0]+xv0[1]+xv0[2]+xv0[3]) + (xv1[0]+xv1[1]+xv1[2]+xv1[3])
                   + (xv2[0]+xv2[1]+xv2[2]+xv2[3]) + (xv3[0]+xv3[1]+xv3[2]+xv3[3])
                   + (xv4[0]+xv4[1]+xv4[2]+xv4[3]) + (xv5[0]+xv5[1]+xv5[2]+xv5[3]);
        lsum += __shfl_xor(lsum, 16, 64);
        lsum += __shfl_xor(lsum, 32, 64);
        const float mu = lsum * (1.0f / 96.0f);
        f32x4 d0 = xv0 - mu, d1 = xv1 - mu, d2 = xv2 - mu,
              d3 = xv3 - mu, d4 = xv4 - mu, d5 = xv5 - mu;
        float lvv = (d0[0]*d0[0]+d0[1]*d0[1]+d0[2]*d0[2]+d0[3]*d0[3])
                  + (d1[0]*d1[0]+d1[1]*d1[1]+d1[2]*d1[2]+d1[3]*d1[3])
                  + (d2[0]*d2[0]+d2[1]*d2[1]+d2[2]*d2[2]+d2[3]*d2[3])
                  + (d3[0]*d3[0]+d3[1]*d3[1]+d3[2]*d3[2]+d3[3]*d3[3])
                  + (d4[0]*d4[0]+d4[1]*d4[1]+d4[2]*d4[2]+d4[3]*d4[3])
                  + (d5[0]*d5[0]+d5[1]*d5[1]+d5[2]*d5[2]+d5[3]*d5[3]);
        lvv += __shfl_xor(lvv, 16, 64);
        lvv += __shfl_xor(lvv, 32, 64);
        const float rstd = rsqrtf(lvv * (1.0f / 96.0f) + EPS_LN) * live;
#pragma unroll
        for (int ks = 0; ks < 3; ++ks) {
            const f32x4 ea = (ks == 0) ? d0 : (ks == 1) ? d2 : d4;
            const f32x4 eb = (ks == 0) ? d1 : (ks == 1) ? d3 : d5;
            f32x4 ga = *(const f32x4*)(g1 + ks * 32 + g4 * 8);
            f32x4 gb = *(const f32x4*)(g1 + ks * 32 + g4 * 8 + 4);
            f32x4 ba = *(const f32x4*)(b1 + ks * 32 + g4 * 8);
            f32x4 bb = *(const f32x4*)(b1 + ks * 32 + g4 * 8 + 4);
            f32x4 y0 = ea * rstd * ga + ba * live;
            f32x4 y1 = eb * rstd * gb + bb * live;
            xa[ks][0] = (unsigned)f2bf(y0[0]) | ((unsigned)f2bf(y0[1]) << 16);
            xa[ks][1] = (unsigned)f2bf(y0[2]) | ((unsigned)f2bf(y0[3]) << 16);
            xa[ks][2] = (unsigned)f2bf(y1[0]) | ((unsigned)f2bf(y1[1]) << 16);
            xa[ks][3] = (unsigned)f2bf(y1[2]) | ((unsigned)f2bf(y1[3]) << 16);
        }
    }

    // ---- QKV: all 18 N-tiles, A from registers; q/k/vt -> per-head slabs ----
#pragma unroll
    for (int sel = 0; sel < 3; ++sel) {
#pragma unroll
        for (int t = 0; t < 6; ++t) {
            const int nt = sel * 6 + t;
            f32x4 acc = {0.f, 0.f, 0.f, 0.f};
#pragma unroll
            for (int ks = 0; ks < 3; ++ks) {
                s16x8 a = __builtin_bit_cast(s16x8, xa[ks]);
                s16x8 bw = *(const s16x8*)(wqkv + (size_t)(nt * 16 + c16) * 96 + ks * 32 + g4 * 8);
                acc = __builtin_amdgcn_mfma_f32_16x16x32_bf16(a, bw, acc, 0, 0, 0);
            }
            const float bias = qkv_b[nt * 16 + c16];
            float v0 = acc[0] + bias, v1 = acc[1] + bias, v2 = acc[2] + bias, v3 = acc[3] + bias;
            if (sel == 0) { v0 *= QSCALE; v1 *= QSCALE; v2 *= QSCALE; v3 *= QSCALE; }
            const int j96 = t * 16 + c16;              // 0..95
            const int h = j96 / 24, d = j96 - h * 24;  // head 0..3, d 0..23
            const int row0 = mt * 16 + g4 * 4;
            if (sel == 0) {
                sm[OFF_Q + h * 3584 + swzQ(row0 + 0, d)] = f2bf(v0);
                sm[OFF_Q + h * 3584 + swzQ(row0 + 1, d)] = f2bf(v1);
                sm[OFF_Q + h * 3584 + swzQ(row0 + 2, d)] = f2bf(v2);
                sm[OFF_Q + h * 3584 + swzQ(row0 + 3, d)] = f2bf(v3);
            } else if (sel == 1) {
                sm[OFF_K + h * 3584 + swzQ(row0 + 0, d)] = f2bf(v0);
                sm[OFF_K + h * 3584 + swzQ(row0 + 1, d)] = f2bf(v1);
                sm[OFF_K + h * 3584 + swzQ(row0 + 2, d)] = f2bf(v2);
                sm[OFF_K + h * 3584 + swzQ(row0 + 3, d)] = f2bf(v3);
            } else {
                sm[OFF_VT + h * 4096 + swzP(d, row0 + 0)] = f2bf(v0);
                sm[OFF_VT + h * 4096 + swzP(d, row0 + 1)] = f2bf(v1);
                sm[OFF_VT + h * 4096 + swzP(d, row0 + 2)] = f2bf(v2);
                sm[OFF_VT + h * 4096 + swzP(d, row0 + 3)] = f2bf(v3);
            }
        }
    }
    __syncthreads();                                   // barrier 2 (q/k/vt complete)

    // ---- 4 heads, barrier-free (each wave touches only its own P rows) ----
    unsigned ogp[4][2][2];
    const int rbase = mt * 16 + g4 * 4;
    int rgs[4];
#pragma unroll
    for (int r = 0; r < 4; ++r) rgs[r] = s_reg[rbase + r];
#pragma unroll
    for (int h = 0; h < 4; ++h) {
        const s16x8 aq = *(const s16x8*)&sm[OFF_Q + h * 3584 + swzQ(mt * 16 + c16, g4 * 8)];
        const float* rh = rpbm + h * 16384;
        float smr[4] = {0.f, 0.f, 0.f, 0.f};
        // streaming no-max softmax: e = exp(s), write unnormalized P, track sum
#pragma unroll
        for (int nt = 0; nt < 7; ++nt) {
            s16x8 bk = *(const s16x8*)&sm[OFF_K + h * 3584 + swzQ(nt * 16 + c16, g4 * 8)];
            f32x4 z = {0.f, 0.f, 0.f, 0.f};
            f32x4 sc = __builtin_amdgcn_mfma_f32_16x16x32_bf16(aq, bk, z, 0, 0, 0);
            const int col = nt * 16 + c16;
            const int creg = s_reg[col];
#pragma unroll
            for (int r = 0; r < 4; ++r) {
                float s = sc[r] + rh[(rbase + r) * 128 + col];
                if (rgs[r] != creg) s -= 100.0f;
                const float e = __expf(s);
                sc[r] = e;
                smr[r] += e;
            }
            sm[OFF_P + swzP(rbase + 0, col)] = f2bf(sc[0]);
            sm[OFF_P + swzP(rbase + 1, col)] = f2bf(sc[1]);
            sm[OFF_P + swzP(rbase + 2, col)] = f2bf(sc[2]);
            sm[OFF_P + swzP(rbase + 3, col)] = f2bf(sc[3]);
        }
#pragma unroll
        for (int r = 0; r < 4; ++r) {
#pragma unroll
            for (int m = 1; m <= 8; m <<= 1) smr[r] += __shfl_xor(smr[r], m, 64);
            smr[r] = 1.0f / fmaxf(smr[r], 1e-30f);     // guard dead pad rows
        }
#pragma unroll
        for (int dt = 0; dt < 2; ++dt) {
            f32x4 acc = {0.f, 0.f, 0.f, 0.f};
#pragma unroll
            for (int ks = 0; ks < 4; ++ks) {
                s16x8 ap = *(const s16x8*)&sm[OFF_P + swzP(mt * 16 + c16, ks * 32 + g4 * 8)];
                s16x8 bv = *(const s16x8*)&sm[OFF_VT + h * 4096 + swzP(dt * 16 + c16, ks * 32 + g4 * 8)];
                acc = __builtin_amdgcn_mfma_f32_16x16x32_bf16(ap, bv, acc, 0, 0, 0);
            }
            ogp[h][dt][0] = (unsigned)f2bf(acc[0] * smr[0]) | ((unsigned)f2bf(acc[1] * smr[1]) << 16);
            ogp[h][dt][1] = (unsigned)f2bf(acc[2] * smr[2]) | ((unsigned)f2bf(acc[3] * smr[3]) << 16);
        }
    }

    // ---- O -> P region (own rows, cols 0..95) — same-wave ordering, no barrier ----
#pragma unroll
    for (int h = 0; h < 4; ++h) {
#pragma unroll
        for (int dt = 0; dt < 2; ++dt) {
            const int d = dt * 16 + c16;
            if (d < 24) {
                const int col = h * 24 + d;
#pragma unroll
                for (int rp = 0; rp < 2; ++rp) {
                    const unsigned u = ogp[h][dt][rp];
                    const int row0 = mt * 16 + g4 * 4 + rp * 2;
                    sm[OFF_P + swzP(row0, col)] = (u16)u;
                    sm[OFF_P + swzP(row0 + 1, col)] = (u16)(u >> 16);
                }
            }
        }
    }

    // ---- proj + residual -> xl2 (reads own P rows only) ----
#pragma unroll
    for (int nt = 0; nt < 6; ++nt) {
        f32x4 acc = {0.f, 0.f, 0.f, 0.f};
#pragma unroll
        for (int ks = 0; ks < 3; ++ks) {
            s16x8 a = *(const s16x8*)&sm[OFF_P + swzP(mt * 16 + c16, ks * 32 + g4 * 8)];
            s16x8 bw = *(const s16x8*)(wproj + (size_t)(nt * 16 + c16) * 96 + ks * 32 + g4 * 8);
            acc = __builtin_amdgcn_mfma_f32_16x16x32_bf16(a, bw, acc, 0, 0, 0);
        }
        const int col = nt * 16 + c16;
        const float pb = proj_b[col];
#pragma unroll
        for (int r = 0; r < 4; ++r) {
            const int row = mt * 16 + g4 * 4 + r;
            if (row < 98) {
                const size_t base = (size_t)s_gtok[row] * C_DIM + col;
                xl2[base] = xl[base] + acc[r] + pb;
            }
        }
    }
}

// ---------------- FFN: LN2 + FC1 + GELU + FC2 + residual + transposed out ----------------
__global__ __launch_bounds__(256) void k_ffn(
    const float* __restrict__ xl2, float* __restrict__ out,
    const float* __restrict__ g2, const float* __restrict__ b2,
    const u16* __restrict__ w1, const float* __restrict__ fc1_b,
    const u16* __restrict__ w2, const float* __restrict__ fc2_b) {
    __shared__ char smem[25088 + 12800];
    u16* s_g = (u16*)smem;                    // [32][392] bf16
    u16* s_h = (u16*)(smem + 25088);          // [32][104] bf16, dead after FC1
    float* s_res = (float*)(smem + 25088);    // [32][100] f32, aliases s_h

    const int tid = threadIdx.x;
    const int lane = tid & 63;
    const int wave = tid >> 6;
    const int g4 = lane >> 4, c16 = lane & 15;
    const int mt = wave & 1;
    const int nh = wave >> 1;
    const int t0 = blockIdx.x * 32;

    for (int n = wave; n < 32; n += 4) {
        const size_t base = (size_t)(t0 + n) * C_DIM;
        const float v0 = xl2[base + lane];
        const float v1 = (lane < 32) ? xl2[base + 64 + lane] : 0.0f;
        const float mu = wave_reduce_sum(v0 + v1) * (1.0f / 96.0f);
        const float d0 = v0 - mu;
        const float d1 = (lane < 32) ? (v1 - mu) : 0.0f;
        const float var = wave_reduce_sum(d0 * d0 + d1 * d1) * (1.0f / 96.0f);
        const float rstd = rsqrtf(var + EPS_LN);
        s_h[n * 104 + lane] = f2bf(d0 * rstd * g2[lane] + b2[lane]);
        if (lane < 32) s_h[n * 104 + 64 + lane] = f2bf(d1 * rstd * g2[64 + lane] + b2[64 + lane]);
    }
    __syncthreads();

#pragma unroll 1
    for (int i = 0; i < 12; ++i) {
        const int nt = nh * 12 + i;
        f32x4 acc = {0.f, 0.f, 0.f, 0.f};
#pragma unroll
        for (int ks = 0; ks < 3; ++ks) {
            s16x8 a = *(const s16x8*)(&s_h[(mt * 16 + c16) * 104 + ks * 32 + g4 * 8]);
            s16x8 bw = *(const s16x8*)(w1 + (size_t)(nt * 16 + c16) * 96 + ks * 32 + g4 * 8);
            acc = __builtin_amdgcn_mfma_f32_16x16x32_bf16(a, bw, acc, 0, 0, 0);
        }
        const int col = nt * 16 + c16;
        const float bias = fc1_b[col];
#pragma unroll
        for (int r = 0; r < 4; ++r) {
            const float v = acc[r] + bias;
            const float gelu = 0.5f * v * (1.0f + erff(v * 0.70710678118654752f));
            s_g[(mt * 16 + g4 * 4 + r) * 392 + col] = f2bf(gelu);
        }
    }
    __syncthreads();

#pragma unroll 1
    for (int i = 0; i < 3; ++i) {
        const int nt = nh * 3 + i;
        f32x4 acc = {0.f, 0.f, 0.f, 0.f};
#pragma unroll
        for (int ks = 0; ks < 12; ++ks) {
            s16x8 a = *(const s16x8*)(&s_g[(mt * 16 + c16) * 392 + ks * 32 + g4 * 8]);
            s16x8 bw = *(const s16x8*)(w2 + (size_t)(nt * 16 + c16) * 384 + ks * 32 + g4 * 8);
            acc = __builtin_amdgcn_mfma_f32_16x16x32_bf16(a, bw, acc, 0, 0, 0);
        }
        const int col = nt * 16 + c16;
        const float bias = fc2_b[col];
#pragma unroll
        for (int r = 0; r < 4; ++r) {
            const int row = mt * 16 + g4 * 4 + r;
            s_res[row * 100 + col] = acc[r] + bias + xl2[(size_t)(t0 + row) * C_DIM + col];
        }
    }
    __syncthreads();

    const int bb = t0 / SPATIAL;
    const int sbase = t0 % SPATIAL;
    for (int idx = tid; idx < 96 * 32; idx += 256) {
        const int c = idx >> 5, tok = idx & 31;
        out[((size_t)bb * C_DIM + c) * SPATIAL + sbase + tok] = s_res[tok * 100 + c];
    }
}

extern "C" void kernel_launch(void* const* d_in, const int* in_sizes, int n_in,
                              void* d_out, int out_size, void* d_ws, size_t ws_size,
                              hipStream_t stream) {
    const float* x      = (const float*)d_in[0];
    const float* g1     = (const float*)d_in[1];
    const float* be1    = (const float*)d_in[2];
    const float* g2     = (const float*)d_in[3];
    const float* be2    = (const float*)d_in[4];
    const float* qkv_w  = (const float*)d_in[5];
    const float* qkv_b  = (const float*)d_in[6];
    const float* proj_w = (const float*)d_in[7];
    const float* proj_b = (const float*)d_in[8];
    const float* rpb    = (const float*)d_in[9];
    const float* fc1_w  = (const float*)d_in[10];
    const float* fc1_b  = (const float*)d_in[11];
    const float* fc2_w  = (const float*)d_in[12];
    const float* fc2_b  = (const float*)d_in[13];
    float* out = (float*)d_out;

    float* xl  = (float*)d_ws;
    float* xl2 = xl + (size_t)NTOK * C_DIM;
    u16* wq = (u16*)(xl2 + (size_t)NTOK * C_DIM);
    u16* wp = wq + 27648;
    u16* w1 = wp + 9216;
    u16* w2 = w1 + 36864;
    float* rpbm = (float*)(w2 + 36864);

    k_prep<<<688, 256, 0, stream>>>(qkv_w, proj_w, fc1_w, fc2_w, rpb, wq, wp, w1, w2, rpbm);
    k_transpose_in<<<dim3(SPATIAL / 32, C_DIM / 32, BATCH), dim3(32, 8), 0, stream>>>(x, xl);
    k_win_attn<<<NWIN_TOT, 448, 0, stream>>>(xl, xl2, g1, be1, wq, qkv_b, wp, proj_b, rpbm);
    k_ffn<<<NTOK / 32, 256, 0, stream>>>(xl2, out, g2, be2, w1, fc1_b, w2, fc2_b);
}